// Round 6
// baseline (319.294 us; speedup 1.0000x reference)
//
#include <hip/hip_runtime.h>
#include <hip/hip_bf16.h>
#include <math.h>

typedef unsigned short u16;
typedef unsigned int   u32;
typedef short bf16x8 __attribute__((ext_vector_type(8)));
typedef float f32x4  __attribute__((ext_vector_type(4)));
typedef float f32x16 __attribute__((ext_vector_type(16)));
typedef u32   u32x4  __attribute__((ext_vector_type(4)));

#define B_   4
#define S_   2048
#define D_   1024
#define H_   16
#define HD_  64
#define M_   (B_*S_)   // 8192 rows

static __device__ __forceinline__ u16 f2bf(float f) {
  __hip_bfloat16 h = __float2bfloat16(f);
  return *reinterpret_cast<u16*>(&h);
}
static __device__ __forceinline__ u32 pack_bf(float lo, float hi) {
  return (u32)f2bf(lo) | ((u32)f2bf(hi) << 16);
}
// truncation pack: [hi.bf16 : lo.bf16] in one v_perm_b32
static __device__ __forceinline__ u32 pack_bf_trunc(float lo, float hi) {
  return __builtin_amdgcn_perm(__float_as_uint(hi), __float_as_uint(lo), 0x07060302u);
}
static __device__ __forceinline__ f32x16 zero16() {
  f32x16 z;
#pragma unroll
  for (int i = 0; i < 16; ++i) z[i] = 0.f;
  return z;
}

// async global->LDS, 16B per lane; lds base must be wave-uniform (lane*16 auto-added)
typedef __attribute__((address_space(1))) const u32* gas_t;
typedef __attribute__((address_space(3))) u32* las_t;
static __device__ __forceinline__ void g2l16(const void* g, void* l) {
  __builtin_amdgcn_global_load_lds((gas_t)g, (las_t)l, 16, 0, 0);
}

// ---------------- fused cast fp32 -> bf16 (x + 4 weights in one launch) ------
__global__ __launch_bounds__(256) void cast_all(const float* __restrict__ x,
                                                const float* __restrict__ Wq,
                                                const float* __restrict__ Wk,
                                                const float* __restrict__ Wv,
                                                const float* __restrict__ Wo,
                                                u16* __restrict__ xb,
                                                u16* __restrict__ Wqb,
                                                u16* __restrict__ Wkb,
                                                u16* __restrict__ Wvb,
                                                u16* __restrict__ Wob) {
  int bid = blockIdx.x;
  const float* src;
  u16* dst;
  int off;
  if (bid < 8192) {                   // x: 8M elems
    src = x; dst = xb; off = bid;
  } else {                            // weights: 1M elems each
    int t = bid - 8192;
    int w = t >> 10;
    off   = t & 1023;
    src = w == 0 ? Wq : w == 1 ? Wk : w == 2 ? Wv : Wo;
    dst = w == 0 ? Wqb : w == 1 ? Wkb : w == 2 ? Wvb : Wob;
  }
  int i = (off * 256 + threadIdx.x) * 4;
  float4 v = *reinterpret_cast<const float4*>(src + i);
  uint2 o;
  o.x = pack_bf(v.x, v.y);
  o.y = pack_bf(v.z, v.w);
  *reinterpret_cast<uint2*>(dst + i) = o;
}

// ---------------- fused QKV GEMM: 3x [8192x1024]x[1024x1024]^T ----------------
// which 0/1 (Q/K): computes C^T = W.x^T (mfma(Wfrag, xfrag)) so each lane's
//   4 C-regs are consecutive n (=d within head) -> one uint2 store per tile.
// which 2 (V): normal orientation, uint2 over 4 consecutive s into Vt[d][s].
__global__ __launch_bounds__(256) void gemm_qkv(const u16* __restrict__ A,
                                                const u16* __restrict__ Wq,
                                                const u16* __restrict__ Wk,
                                                const u16* __restrict__ Wv,
                                                const float* __restrict__ bq,
                                                const float* __restrict__ bk,
                                                const float* __restrict__ bv,
                                                u16* __restrict__ Qo,
                                                u16* __restrict__ Ko,
                                                u16* __restrict__ Vo) {
  const int tid  = threadIdx.x;
  const int lane = tid & 63;
  const int wave = tid >> 6;
  const int m16  = lane & 15;
  const int quad = lane >> 4;
  const int wm   = wave & 1;
  const int wn   = wave >> 1;
  const int which = blockIdx.x % 3;
  const int m0   = (blockIdx.x / 3) * 128;
  const int n0   = blockIdx.y * 128;

  const u16* W = which == 0 ? Wq : which == 1 ? Wk : Wv;
  const float* bias = which == 0 ? bq : which == 1 ? bk : bv;

  __shared__ __align__(16) u16 As[128 * 32];
  __shared__ __align__(16) u16 Bs[128 * 32];

  f32x4 acc[4][4];
#pragma unroll
  for (int i = 0; i < 4; ++i)
#pragma unroll
    for (int j = 0; j < 4; ++j) acc[i][j] = (f32x4){0.f, 0.f, 0.f, 0.f};

  for (int k0 = 0; k0 < 1024; k0 += 32) {
#pragma unroll
    for (int i = 0; i < 2; ++i) {
      int e0  = i * 256 + (wave << 6);
      int e   = e0 + lane;
      int row = e >> 2;
      int c8  = (e & 3) * 8;
      g2l16(&A[(size_t)(m0 + row) * 1024 + k0 + c8], &As[e0 * 8]);
      g2l16(&W[(size_t)(n0 + row) * 1024 + k0 + c8], &Bs[e0 * 8]);
    }
    __syncthreads();

    bf16x8 af[4], bfr[4];
#pragma unroll
    for (int mt = 0; mt < 4; ++mt)
      af[mt] = *reinterpret_cast<const bf16x8*>(&As[(wm * 64 + mt * 16 + m16) * 32 + quad * 8]);
#pragma unroll
    for (int nt = 0; nt < 4; ++nt)
      bfr[nt] = *reinterpret_cast<const bf16x8*>(&Bs[(wn * 64 + nt * 16 + m16) * 32 + quad * 8]);

    if (which < 2) {
#pragma unroll
      for (int mt = 0; mt < 4; ++mt)
#pragma unroll
        for (int nt = 0; nt < 4; ++nt)
          acc[mt][nt] = __builtin_amdgcn_mfma_f32_16x16x32_bf16(bfr[nt], af[mt], acc[mt][nt], 0, 0, 0);
    } else {
#pragma unroll
      for (int mt = 0; mt < 4; ++mt)
#pragma unroll
        for (int nt = 0; nt < 4; ++nt)
          acc[mt][nt] = __builtin_amdgcn_mfma_f32_16x16x32_bf16(af[mt], bfr[nt], acc[mt][nt], 0, 0, 0);
    }
    __syncthreads();
  }

  const float scale = which == 0 ? 0.125f * 1.44269504f : 1.0f;
  u16* ob = which == 0 ? Qo : which == 1 ? Ko : Vo;
  if (which < 2) {
    // C^T: row = n = nb+r (4 consecutive d), col = m (= s)
#pragma unroll
    for (int nt = 0; nt < 4; ++nt) {
      int nb = n0 + wn * 64 + nt * 16 + quad * 4;
      float4 b4 = *reinterpret_cast<const float4*>(&bias[nb]);
      int h = nb >> 6, d0 = nb & 63;
#pragma unroll
      for (int mt = 0; mt < 4; ++mt) {
        int m = m0 + wm * 64 + mt * 16 + m16;
        int b = m >> 11, s = m & 2047;
        float v0 = (acc[mt][nt][0] + b4.x) * scale;
        float v1 = (acc[mt][nt][1] + b4.y) * scale;
        float v2 = (acc[mt][nt][2] + b4.z) * scale;
        float v3 = (acc[mt][nt][3] + b4.w) * scale;
        uint2 w;
        w.x = pack_bf(v0, v1);
        w.y = pack_bf(v2, v3);
        *reinterpret_cast<uint2*>(&ob[(size_t)((b * H_ + h) * S_ + s) * HD_ + d0]) = w;
      }
    }
  } else {
#pragma unroll
    for (int mt = 0; mt < 4; ++mt) {
#pragma unroll
      for (int nt = 0; nt < 4; ++nt) {
        int col = n0 + wn * 64 + nt * 16 + m16;
        float bi = bias[col];
        int row0 = m0 + wm * 64 + mt * 16 + quad * 4;
        int b = row0 >> 11, s = row0 & 2047;
        int h = col >> 6,  d = col & 63;
        uint2 w;
        w.x = pack_bf(acc[mt][nt][0] + bi, acc[mt][nt][1] + bi);
        w.y = pack_bf(acc[mt][nt][2] + bi, acc[mt][nt][3] + bi);
        *reinterpret_cast<uint2*>(&ob[(size_t)((b * H_ + h) * HD_ + d) * S_ + s]) = w;
      }
    }
  }
}

// ---------------- O-projection GEMM (fp32 out), C^T orientation --------------
__global__ __launch_bounds__(256) void gemm_bt(const u16* __restrict__ A,
                                               const u16* __restrict__ W,
                                               const float* __restrict__ bias,
                                               float* __restrict__ out) {
  const int tid  = threadIdx.x;
  const int lane = tid & 63;
  const int wave = tid >> 6;
  const int m16  = lane & 15;
  const int quad = lane >> 4;
  const int wm   = wave & 1;
  const int wn   = wave >> 1;
  const int m0   = blockIdx.x * 128;
  const int n0   = blockIdx.y * 128;

  __shared__ __align__(16) u16 As[128 * 32];
  __shared__ __align__(16) u16 Bs[128 * 32];

  f32x4 acc[4][4];
#pragma unroll
  for (int i = 0; i < 4; ++i)
#pragma unroll
    for (int j = 0; j < 4; ++j) acc[i][j] = (f32x4){0.f, 0.f, 0.f, 0.f};

  for (int k0 = 0; k0 < 1024; k0 += 32) {
#pragma unroll
    for (int i = 0; i < 2; ++i) {
      int e0  = i * 256 + (wave << 6);
      int e   = e0 + lane;
      int row = e >> 2;
      int c8  = (e & 3) * 8;
      g2l16(&A[(size_t)(m0 + row) * 1024 + k0 + c8], &As[e0 * 8]);
      g2l16(&W[(size_t)(n0 + row) * 1024 + k0 + c8], &Bs[e0 * 8]);
    }
    __syncthreads();

    bf16x8 af[4], bfr[4];
#pragma unroll
    for (int mt = 0; mt < 4; ++mt)
      af[mt] = *reinterpret_cast<const bf16x8*>(&As[(wm * 64 + mt * 16 + m16) * 32 + quad * 8]);
#pragma unroll
    for (int nt = 0; nt < 4; ++nt)
      bfr[nt] = *reinterpret_cast<const bf16x8*>(&Bs[(wn * 64 + nt * 16 + m16) * 32 + quad * 8]);

#pragma unroll
    for (int mt = 0; mt < 4; ++mt)
#pragma unroll
      for (int nt = 0; nt < 4; ++nt)
        acc[mt][nt] = __builtin_amdgcn_mfma_f32_16x16x32_bf16(bfr[nt], af[mt], acc[mt][nt], 0, 0, 0);
    __syncthreads();
  }

  // C^T epilogue: lane holds 4 consecutive n for fixed m -> float4 store
#pragma unroll
  for (int nt = 0; nt < 4; ++nt) {
    int nb = n0 + wn * 64 + nt * 16 + quad * 4;
    float4 b4 = *reinterpret_cast<const float4*>(&bias[nb]);
#pragma unroll
    for (int mt = 0; mt < 4; ++mt) {
      int m = m0 + wm * 64 + mt * 16 + m16;
      float4 o;
      o.x = acc[mt][nt][0] + b4.x;
      o.y = acc[mt][nt][1] + b4.y;
      o.z = acc[mt][nt][2] + b4.z;
      o.w = acc[mt][nt][3] + b4.w;
      *reinterpret_cast<float4*>(&out[(size_t)m * 1024 + nb]) = o;
    }
  }
}

// ---------------- flash attention: dbuf LDS, 1 barrier/ktile -----------------
// Q: [bh,s,d] bf16 pre-scaled by log2e/8; K: [bh,s,d] bf16; Vt: [bh,d,s] bf16
// out: bf16 [b, s, h*64+d]. S^T = K.Q^T; fixed-max softmax; register P-transpose.
// Tile rotation: compute buf[p] | write regs(t+1)->buf[1-p] | load t+2 -> regs.
static __device__ __forceinline__ void attn_compute(const u16* __restrict__ ks,
                                                    const u16* __restrict__ vs,
                                                    const bf16x8 qf[4],
                                                    int r32, int h32,
                                                    f32x16& a0, f32x16& a1,
                                                    float& lsum) {
  f32x16 sc[2];
#pragma unroll
  for (int nt = 0; nt < 2; ++nt) {
    sc[nt] = zero16();
#pragma unroll
    for (int dc = 0; dc < 4; ++dc) {
      bf16x8 kf = *reinterpret_cast<const bf16x8*>(&ks[(nt * 32 + r32) * 72 + dc * 16 + h32 * 8]);
      sc[nt] = __builtin_amdgcn_mfma_f32_32x32x16_bf16(kf, qf[dc], sc[nt], 0, 0, 0);
    }
  }
  u32 pk[2][8];
  float ps = 0.f;
#pragma unroll
  for (int nt = 0; nt < 2; ++nt)
#pragma unroll
    for (int i = 0; i < 8; ++i) {
      float p0 = __builtin_amdgcn_exp2f(sc[nt][2 * i]);
      float p1 = __builtin_amdgcn_exp2f(sc[nt][2 * i + 1]);
      ps += p0 + p1;
      pk[nt][i] = pack_bf_trunc(p0, p1);
    }
  lsum += ps;
#pragma unroll
  for (int nt = 0; nt < 2; ++nt) {
#pragma unroll
    for (int kc2 = 0; kc2 < 2; ++kc2) {
      u32 s0 = h32 ? pk[nt][4 * kc2 + 0] : pk[nt][4 * kc2 + 2];
      u32 s1 = h32 ? pk[nt][4 * kc2 + 1] : pk[nt][4 * kc2 + 3];
      u32 x0 = (u32)__shfl_xor((int)s0, 32);
      u32 x1 = (u32)__shfl_xor((int)s1, 32);
      u32x4 bw;
      bw[0] = h32 ? x0 : pk[nt][4 * kc2 + 0];
      bw[1] = h32 ? x1 : pk[nt][4 * kc2 + 1];
      bw[2] = h32 ? pk[nt][4 * kc2 + 2] : x0;
      bw[3] = h32 ? pk[nt][4 * kc2 + 3] : x1;
      bf16x8 pfrag = *reinterpret_cast<bf16x8*>(&bw);
      const int kc = nt * 2 + kc2;
      bf16x8 vf0 = *reinterpret_cast<const bf16x8*>(&vs[(r32) * 72 + kc * 16 + h32 * 8]);
      bf16x8 vf1 = *reinterpret_cast<const bf16x8*>(&vs[(32 + r32) * 72 + kc * 16 + h32 * 8]);
      a0 = __builtin_amdgcn_mfma_f32_32x32x16_bf16(vf0, pfrag, a0, 0, 0, 0);
      a1 = __builtin_amdgcn_mfma_f32_32x32x16_bf16(vf1, pfrag, a1, 0, 0, 0);
    }
  }
}

__global__ __launch_bounds__(256, 4) void attn_kernel(const u16* __restrict__ Q,
                                                      const u16* __restrict__ K,
                                                      const u16* __restrict__ Vt,
                                                      u16* __restrict__ out) {
  const int tid  = threadIdx.x;
  const int lane = tid & 63;
  const int wave = tid >> 6;
  const int r32  = lane & 31;
  const int h32  = lane >> 5;
  const int bh   = blockIdx.y;
  const int q0   = blockIdx.x * 128 + wave * 32;

  __shared__ __align__(16) u16 Ks[2][64 * 72];   // stride 72 -> conflict-free
  __shared__ __align__(16) u16 Vs[2][64 * 72];

  const u16* kbase = K  + (size_t)bh * S_ * HD_;
  const u16* vbase = Vt + (size_t)bh * HD_ * S_;
  const int ra = tid >> 3;             // rows 0..31
  const int rb = ra + 32;              // rows 32..63
  const int ca = (tid & 7) * 8;

  bf16x8 qf[4];
  {
    const u16* qbase = Q + (size_t)(bh * S_ + q0 + r32) * HD_ + h32 * 8;
#pragma unroll
    for (int dc = 0; dc < 4; ++dc)
      qf[dc] = *reinterpret_cast<const bf16x8*>(qbase + dc * 16);
  }

  f32x16 a0 = zero16(), a1 = zero16();
  float lsum = 0.f;

  // prologue: tile 0 -> set0 -> buf0; tile 1 -> set1
  uint4 k0a = *reinterpret_cast<const uint4*>(&kbase[(size_t)ra * HD_ + ca]);
  uint4 k0b = *reinterpret_cast<const uint4*>(&kbase[(size_t)rb * HD_ + ca]);
  uint4 v0a = *reinterpret_cast<const uint4*>(&vbase[(size_t)ra * S_ + ca]);
  uint4 v0b = *reinterpret_cast<const uint4*>(&vbase[(size_t)rb * S_ + ca]);
  *reinterpret_cast<uint4*>(&Ks[0][ra * 72 + ca]) = k0a;
  *reinterpret_cast<uint4*>(&Ks[0][rb * 72 + ca]) = k0b;
  *reinterpret_cast<uint4*>(&Vs[0][ra * 72 + ca]) = v0a;
  *reinterpret_cast<uint4*>(&Vs[0][rb * 72 + ca]) = v0b;
  uint4 k1a = *reinterpret_cast<const uint4*>(&kbase[(size_t)(64 + ra) * HD_ + ca]);
  uint4 k1b = *reinterpret_cast<const uint4*>(&kbase[(size_t)(64 + rb) * HD_ + ca]);
  uint4 v1a = *reinterpret_cast<const uint4*>(&vbase[(size_t)ra * S_ + 64 + ca]);
  uint4 v1b = *reinterpret_cast<const uint4*>(&vbase[(size_t)rb * S_ + 64 + ca]);
  __syncthreads();

  const int NT = S_ / 64;   // 32, even
  for (int kt = 0; kt < NT; kt += 2) {
    // ---- even: compute buf0, write set1 -> buf1, load kt+2 -> set0 ----
    attn_compute(Ks[0], Vs[0], qf, r32, h32, a0, a1, lsum);
    *reinterpret_cast<uint4*>(&Ks[1][ra * 72 + ca]) = k1a;
    *reinterpret_cast<uint4*>(&Ks[1][rb * 72 + ca]) = k1b;
    *reinterpret_cast<uint4*>(&Vs[1][ra * 72 + ca]) = v1a;
    *reinterpret_cast<uint4*>(&Vs[1][rb * 72 + ca]) = v1b;
    {
      int kn = (kt + 2 < NT ? kt + 2 : NT - 1) * 64;
      k0a = *reinterpret_cast<const uint4*>(&kbase[(size_t)(kn + ra) * HD_ + ca]);
      k0b = *reinterpret_cast<const uint4*>(&kbase[(size_t)(kn + rb) * HD_ + ca]);
      v0a = *reinterpret_cast<const uint4*>(&vbase[(size_t)ra * S_ + kn + ca]);
      v0b = *reinterpret_cast<const uint4*>(&vbase[(size_t)rb * S_ + kn + ca]);
    }
    __syncthreads();

    // ---- odd: compute buf1, write set0 -> buf0, load kt+3 -> set1 ----
    attn_compute(Ks[1], Vs[1], qf, r32, h32, a0, a1, lsum);
    *reinterpret_cast<uint4*>(&Ks[0][ra * 72 + ca]) = k0a;
    *reinterpret_cast<uint4*>(&Ks[0][rb * 72 + ca]) = k0b;
    *reinterpret_cast<uint4*>(&Vs[0][ra * 72 + ca]) = v0a;
    *reinterpret_cast<uint4*>(&Vs[0][rb * 72 + ca]) = v0b;
    {
      int kn = (kt + 3 < NT ? kt + 3 : NT - 1) * 64;
      k1a = *reinterpret_cast<const uint4*>(&kbase[(size_t)(kn + ra) * HD_ + ca]);
      k1b = *reinterpret_cast<const uint4*>(&kbase[(size_t)(kn + rb) * HD_ + ca]);
      v1a = *reinterpret_cast<const uint4*>(&vbase[(size_t)ra * S_ + kn + ca]);
      v1b = *reinterpret_cast<const uint4*>(&vbase[(size_t)rb * S_ + kn + ca]);
    }
    __syncthreads();
  }

  // epilogue: O^T regs -> out[b, s, h*64+d]; d = dt*32 + 8g + 4*h32 + (0..3)
  const int b = bh >> 4, hh = bh & 15;
  float lt  = lsum + __shfl_xor(lsum, 32);
  float inv = 1.f / lt;
  int srow = q0 + r32;
  u16* orow = out + (size_t)(b * S_ + srow) * D_ + hh * HD_;
#pragma unroll
  for (int g = 0; g < 4; ++g) {
    uint2 w;
    w.x = pack_bf(a0[4 * g + 0] * inv, a0[4 * g + 1] * inv);
    w.y = pack_bf(a0[4 * g + 2] * inv, a0[4 * g + 3] * inv);
    *reinterpret_cast<uint2*>(orow + 8 * g + 4 * h32) = w;
    w.x = pack_bf(a1[4 * g + 0] * inv, a1[4 * g + 1] * inv);
    w.y = pack_bf(a1[4 * g + 2] * inv, a1[4 * g + 3] * inv);
    *reinterpret_cast<uint2*>(orow + 32 + 8 * g + 4 * h32) = w;
  }
}

// ---------------- layernorm ----------------
__global__ __launch_bounds__(256) void ln_kernel(const float* __restrict__ X,
                                                 const float* __restrict__ w,
                                                 const float* __restrict__ b,
                                                 float* __restrict__ out) {
  const int row = blockIdx.x;
  const int tid = threadIdx.x;
  const float* x = X + (size_t)row * 1024;
  float vals[4];
  float s = 0.f, s2 = 0.f;
#pragma unroll
  for (int i = 0; i < 4; ++i) {
    float v = x[tid + i * 256];
    vals[i] = v;
    s += v;
    s2 += v * v;
  }
#pragma unroll
  for (int off = 32; off; off >>= 1) {
    s  += __shfl_xor(s, off);
    s2 += __shfl_xor(s2, off);
  }
  __shared__ float a1[4], a2[4];
  if ((tid & 63) == 0) { a1[tid >> 6] = s; a2[tid >> 6] = s2; }
  __syncthreads();
  s  = a1[0] + a1[1] + a1[2] + a1[3];
  s2 = a2[0] + a2[1] + a2[2] + a2[3];
  float mu  = s * (1.f / 1024.f);
  float var = s2 * (1.f / 1024.f) - mu * mu;
  float inv = rsqrtf(var + 1e-5f);
#pragma unroll
  for (int i = 0; i < 4; ++i) {
    int c = tid + i * 256;
    out[(size_t)row * 1024 + c] = (vals[i] - mu) * inv * w[c] + b[c];
  }
}

// ---------------- launch ----------------
extern "C" void kernel_launch(void* const* d_in, const int* in_sizes, int n_in,
                              void* d_out, int out_size, void* d_ws, size_t ws_size,
                              hipStream_t stream) {
  const float* x   = (const float*)d_in[0];
  const float* Wq  = (const float*)d_in[1];
  const float* bq  = (const float*)d_in[2];
  const float* Wk  = (const float*)d_in[3];
  const float* bk  = (const float*)d_in[4];
  const float* Wv  = (const float*)d_in[5];
  const float* bv  = (const float*)d_in[6];
  const float* Wo  = (const float*)d_in[7];
  const float* bo  = (const float*)d_in[8];
  const float* lnw = (const float*)d_in[9];
  const float* lnb = (const float*)d_in[10];

  const size_t MB = 1024ull * 1024ull;
  char* ws = (char*)d_ws;
  u16* xb  = (u16*)(ws + 0);        // 16 MB; later reused as attention output
  u16* Qb  = (u16*)(ws + 16 * MB);  // 16 MB
  u16* Kb  = (u16*)(ws + 32 * MB);  // 16 MB
  u16* Vtb = (u16*)(ws + 48 * MB);  // 16 MB
  u16* Wqb = (u16*)(ws + 64 * MB);  // 2 MB each
  u16* Wkb = (u16*)(ws + 66 * MB);
  u16* Wvb = (u16*)(ws + 68 * MB);
  u16* Wob = (u16*)(ws + 70 * MB);
  float* Of = (float*)(ws + 16 * MB); // 32 MB, overlaps Qb/Kb (dead after attention)

  cast_all<<<8192 + 4096, 256, 0, stream>>>(x, Wq, Wk, Wv, Wo, xb, Wqb, Wkb, Wvb, Wob);

  gemm_qkv<<<dim3((M_ / 128) * 3, D_ / 128), 256, 0, stream>>>(
      xb, Wqb, Wkb, Wvb, bq, bk, bv, Qb, Kb, Vtb);

  attn_kernel<<<dim3(S_ / 128, B_ * H_), 256, 0, stream>>>(Qb, Kb, Vtb, xb);

  gemm_bt<<<dim3(M_ / 128, D_ / 128), 256, 0, stream>>>(xb, Wob, bo, Of);

  ln_kernel<<<M_, 256, 0, stream>>>(Of, lnw, lnb, (float*)d_out);
}

// Round 7
// 307.239 us; speedup vs baseline: 1.0392x; 1.0392x over previous
//
#include <hip/hip_runtime.h>
#include <hip/hip_bf16.h>
#include <math.h>

typedef unsigned short u16;
typedef unsigned int   u32;
typedef short bf16x8 __attribute__((ext_vector_type(8)));
typedef float f32x4  __attribute__((ext_vector_type(4)));
typedef float f32x16 __attribute__((ext_vector_type(16)));
typedef u32   u32x4  __attribute__((ext_vector_type(4)));

#define B_   4
#define S_   2048
#define D_   1024
#define H_   16
#define HD_  64
#define M_   (B_*S_)   // 8192 rows

static __device__ __forceinline__ u16 f2bf(float f) {
  __hip_bfloat16 h = __float2bfloat16(f);
  return *reinterpret_cast<u16*>(&h);
}
static __device__ __forceinline__ u32 pack_bf(float lo, float hi) {
  return (u32)f2bf(lo) | ((u32)f2bf(hi) << 16);
}
// truncation pack: [hi.bf16 : lo.bf16] in one v_perm_b32
static __device__ __forceinline__ u32 pack_bf_trunc(float lo, float hi) {
  return __builtin_amdgcn_perm(__float_as_uint(hi), __float_as_uint(lo), 0x07060302u);
}
static __device__ __forceinline__ f32x16 zero16() {
  f32x16 z;
#pragma unroll
  for (int i = 0; i < 16; ++i) z[i] = 0.f;
  return z;
}

// async global->LDS, 16B per lane; lds base must be wave-uniform (lane*16 auto-added)
typedef __attribute__((address_space(1))) const u32* gas_t;
typedef __attribute__((address_space(3))) u32* las_t;
static __device__ __forceinline__ void g2l16(const void* g, void* l) {
  __builtin_amdgcn_global_load_lds((gas_t)g, (las_t)l, 16, 0, 0);
}

// ---------------- fused cast fp32 -> bf16 (x + 4 weights in one launch) ------
__global__ __launch_bounds__(256) void cast_all(const float* __restrict__ x,
                                                const float* __restrict__ Wq,
                                                const float* __restrict__ Wk,
                                                const float* __restrict__ Wv,
                                                const float* __restrict__ Wo,
                                                u16* __restrict__ xb,
                                                u16* __restrict__ Wqb,
                                                u16* __restrict__ Wkb,
                                                u16* __restrict__ Wvb,
                                                u16* __restrict__ Wob) {
  int bid = blockIdx.x;
  const float* src;
  u16* dst;
  int off;
  if (bid < 8192) {                   // x: 8M elems
    src = x; dst = xb; off = bid;
  } else {                            // weights: 1M elems each
    int t = bid - 8192;
    int w = t >> 10;
    off   = t & 1023;
    src = w == 0 ? Wq : w == 1 ? Wk : w == 2 ? Wv : Wo;
    dst = w == 0 ? Wqb : w == 1 ? Wkb : w == 2 ? Wvb : Wob;
  }
  int i = (off * 256 + threadIdx.x) * 4;
  float4 v = *reinterpret_cast<const float4*>(src + i);
  uint2 o;
  o.x = pack_bf(v.x, v.y);
  o.y = pack_bf(v.z, v.w);
  *reinterpret_cast<uint2*>(dst + i) = o;
}

// ---------------- shared GEMM K-loop (XOR-swizzled LDS chunks) ---------------
// Staging: slot e holds row=e>>2, logical chunk (e&3)^((e>>3)&3) -> frag reads
// of (row=m16, chunk=quad) start at bank 16*(m16&1)+4*(quad^((m16>>1)&3)):
// all 8 bank-groups covered, 2 lanes each -> conflict-free (2-way is free).
// TRANS=true computes C^T via mfma(bfr, af); branch is OUTSIDE the loop.
template <bool TRANS>
static __device__ __forceinline__ void gemm_loop(const u16* __restrict__ A,
                                                 const u16* __restrict__ W,
                                                 u16* As, u16* Bs,
                                                 int m0, int n0,
                                                 int wave, int lane,
                                                 f32x4 (&acc)[4][4]) {
  const int m16  = lane & 15;
  const int quad = lane >> 4;
  const int wm   = wave & 1;
  const int wn   = wave >> 1;
  const int psw  = (quad ^ ((m16 >> 1) & 3)) * 8;   // swizzled physical chunk

  for (int k0 = 0; k0 < 1024; k0 += 32) {
#pragma unroll
    for (int i = 0; i < 2; ++i) {
      int e0  = i * 256 + (wave << 6);
      int e   = e0 + lane;
      int row = e >> 2;
      int c8  = ((e & 3) ^ ((e >> 3) & 3)) * 8;     // swizzled logical chunk
      g2l16(&A[(size_t)(m0 + row) * 1024 + k0 + c8], &As[e0 * 8]);
      g2l16(&W[(size_t)(n0 + row) * 1024 + k0 + c8], &Bs[e0 * 8]);
    }
    __syncthreads();

    bf16x8 af[4], bfr[4];
#pragma unroll
    for (int mt = 0; mt < 4; ++mt)
      af[mt] = *reinterpret_cast<const bf16x8*>(&As[(wm * 64 + mt * 16 + m16) * 32 + psw]);
#pragma unroll
    for (int nt = 0; nt < 4; ++nt)
      bfr[nt] = *reinterpret_cast<const bf16x8*>(&Bs[(wn * 64 + nt * 16 + m16) * 32 + psw]);

#pragma unroll
    for (int mt = 0; mt < 4; ++mt)
#pragma unroll
      for (int nt = 0; nt < 4; ++nt)
        acc[mt][nt] = TRANS
            ? __builtin_amdgcn_mfma_f32_16x16x32_bf16(bfr[nt], af[mt], acc[mt][nt], 0, 0, 0)
            : __builtin_amdgcn_mfma_f32_16x16x32_bf16(af[mt], bfr[nt], acc[mt][nt], 0, 0, 0);
    __syncthreads();
  }
}

// ---------------- fused QKV GEMM: 3x [8192x1024]x[1024x1024]^T ----------------
// which 0/1 (Q/K): C^T path -> lane holds 4 consecutive d -> one uint2 store.
// which 2 (V): normal path -> uint2 over 4 consecutive s into Vt[d][s].
__global__ __launch_bounds__(256) void gemm_qkv(const u16* __restrict__ A,
                                                const u16* __restrict__ Wq,
                                                const u16* __restrict__ Wk,
                                                const u16* __restrict__ Wv,
                                                const float* __restrict__ bq,
                                                const float* __restrict__ bk,
                                                const float* __restrict__ bv,
                                                u16* __restrict__ Qo,
                                                u16* __restrict__ Ko,
                                                u16* __restrict__ Vo) {
  const int tid  = threadIdx.x;
  const int lane = tid & 63;
  const int wave = tid >> 6;
  const int m16  = lane & 15;
  const int quad = lane >> 4;
  const int wm   = wave & 1;
  const int wn   = wave >> 1;
  const int which = blockIdx.x % 3;
  const int m0   = (blockIdx.x / 3) * 128;
  const int n0   = blockIdx.y * 128;

  const u16* W = which == 0 ? Wq : which == 1 ? Wk : Wv;
  const float* bias = which == 0 ? bq : which == 1 ? bk : bv;

  __shared__ __align__(16) u16 As[128 * 32];
  __shared__ __align__(16) u16 Bs[128 * 32];

  f32x4 acc[4][4];
#pragma unroll
  for (int i = 0; i < 4; ++i)
#pragma unroll
    for (int j = 0; j < 4; ++j) acc[i][j] = (f32x4){0.f, 0.f, 0.f, 0.f};

  if (which < 2) {
    gemm_loop<true>(A, W, As, Bs, m0, n0, wave, lane, acc);
    const float scale = which == 0 ? 0.125f * 1.44269504f : 1.0f;
    u16* ob = which == 0 ? Qo : Ko;
    // C^T: lane's 4 C-regs = consecutive n (= d within head), col = m (= s)
#pragma unroll
    for (int nt = 0; nt < 4; ++nt) {
      int nb = n0 + wn * 64 + nt * 16 + quad * 4;
      float4 b4 = *reinterpret_cast<const float4*>(&bias[nb]);
      int h = nb >> 6, d0 = nb & 63;
#pragma unroll
      for (int mt = 0; mt < 4; ++mt) {
        int m = m0 + wm * 64 + mt * 16 + m16;
        int b = m >> 11, s = m & 2047;
        uint2 w;
        w.x = pack_bf((acc[mt][nt][0] + b4.x) * scale, (acc[mt][nt][1] + b4.y) * scale);
        w.y = pack_bf((acc[mt][nt][2] + b4.z) * scale, (acc[mt][nt][3] + b4.w) * scale);
        *reinterpret_cast<uint2*>(&ob[(size_t)((b * H_ + h) * S_ + s) * HD_ + d0]) = w;
      }
    }
  } else {
    gemm_loop<false>(A, W, As, Bs, m0, n0, wave, lane, acc);
#pragma unroll
    for (int mt = 0; mt < 4; ++mt) {
#pragma unroll
      for (int nt = 0; nt < 4; ++nt) {
        int col = n0 + wn * 64 + nt * 16 + m16;
        float bi = bias[col];
        int row0 = m0 + wm * 64 + mt * 16 + quad * 4;
        int b = row0 >> 11, s = row0 & 2047;
        int h = col >> 6,  d = col & 63;
        uint2 w;
        w.x = pack_bf(acc[mt][nt][0] + bi, acc[mt][nt][1] + bi);
        w.y = pack_bf(acc[mt][nt][2] + bi, acc[mt][nt][3] + bi);
        *reinterpret_cast<uint2*>(&Vo[(size_t)((b * H_ + h) * HD_ + d) * S_ + s]) = w;
      }
    }
  }
}

// ---------------- O-projection GEMM (fp32 out), C^T + float4 stores ----------
__global__ __launch_bounds__(256) void gemm_bt(const u16* __restrict__ A,
                                               const u16* __restrict__ W,
                                               const float* __restrict__ bias,
                                               float* __restrict__ out) {
  const int tid  = threadIdx.x;
  const int lane = tid & 63;
  const int wave = tid >> 6;
  const int m16  = lane & 15;
  const int quad = lane >> 4;
  const int wm   = wave & 1;
  const int wn   = wave >> 1;
  const int m0   = blockIdx.x * 128;
  const int n0   = blockIdx.y * 128;

  __shared__ __align__(16) u16 As[128 * 32];
  __shared__ __align__(16) u16 Bs[128 * 32];

  f32x4 acc[4][4];
#pragma unroll
  for (int i = 0; i < 4; ++i)
#pragma unroll
    for (int j = 0; j < 4; ++j) acc[i][j] = (f32x4){0.f, 0.f, 0.f, 0.f};

  gemm_loop<true>(A, W, As, Bs, m0, n0, wave, lane, acc);

  // C^T epilogue: lane holds 4 consecutive n for fixed m -> float4 store
#pragma unroll
  for (int nt = 0; nt < 4; ++nt) {
    int nb = n0 + wn * 64 + nt * 16 + quad * 4;
    float4 b4 = *reinterpret_cast<const float4*>(&bias[nb]);
#pragma unroll
    for (int mt = 0; mt < 4; ++mt) {
      int m = m0 + wm * 64 + mt * 16 + m16;
      float4 o;
      o.x = acc[mt][nt][0] + b4.x;
      o.y = acc[mt][nt][1] + b4.y;
      o.z = acc[mt][nt][2] + b4.z;
      o.w = acc[mt][nt][3] + b4.w;
      *reinterpret_cast<float4*>(&out[(size_t)m * 1024 + nb]) = o;
    }
  }
}

// ---------------- flash attention: dbuf LDS, 1 barrier/ktile -----------------
// Q: [bh,s,d] bf16 pre-scaled by log2e/8; K: [bh,s,d] bf16; Vt: [bh,d,s] bf16
// out: bf16 [b, s, h*64+d]. S^T = K.Q^T; fixed-max softmax; register P-transpose.
// Tile rotation: compute buf[p] | write regs(t+1)->buf[1-p] | load t+2 -> regs.
static __device__ __forceinline__ void attn_compute(const u16* __restrict__ ks,
                                                    const u16* __restrict__ vs,
                                                    const bf16x8 qf[4],
                                                    int r32, int h32,
                                                    f32x16& a0, f32x16& a1,
                                                    float& lsum) {
  f32x16 sc[2];
#pragma unroll
  for (int nt = 0; nt < 2; ++nt) {
    sc[nt] = zero16();
#pragma unroll
    for (int dc = 0; dc < 4; ++dc) {
      bf16x8 kf = *reinterpret_cast<const bf16x8*>(&ks[(nt * 32 + r32) * 72 + dc * 16 + h32 * 8]);
      sc[nt] = __builtin_amdgcn_mfma_f32_32x32x16_bf16(kf, qf[dc], sc[nt], 0, 0, 0);
    }
  }
  u32 pk[2][8];
  float ps = 0.f;
#pragma unroll
  for (int nt = 0; nt < 2; ++nt)
#pragma unroll
    for (int i = 0; i < 8; ++i) {
      float p0 = __builtin_amdgcn_exp2f(sc[nt][2 * i]);
      float p1 = __builtin_amdgcn_exp2f(sc[nt][2 * i + 1]);
      ps += p0 + p1;
      pk[nt][i] = pack_bf_trunc(p0, p1);
    }
  lsum += ps;
#pragma unroll
  for (int nt = 0; nt < 2; ++nt) {
#pragma unroll
    for (int kc2 = 0; kc2 < 2; ++kc2) {
      u32 s0 = h32 ? pk[nt][4 * kc2 + 0] : pk[nt][4 * kc2 + 2];
      u32 s1 = h32 ? pk[nt][4 * kc2 + 1] : pk[nt][4 * kc2 + 3];
      u32 x0 = (u32)__shfl_xor((int)s0, 32);
      u32 x1 = (u32)__shfl_xor((int)s1, 32);
      u32x4 bw;
      bw[0] = h32 ? x0 : pk[nt][4 * kc2 + 0];
      bw[1] = h32 ? x1 : pk[nt][4 * kc2 + 1];
      bw[2] = h32 ? pk[nt][4 * kc2 + 2] : x0;
      bw[3] = h32 ? pk[nt][4 * kc2 + 3] : x1;
      bf16x8 pfrag = *reinterpret_cast<bf16x8*>(&bw);
      const int kc = nt * 2 + kc2;
      bf16x8 vf0 = *reinterpret_cast<const bf16x8*>(&vs[(r32) * 72 + kc * 16 + h32 * 8]);
      bf16x8 vf1 = *reinterpret_cast<const bf16x8*>(&vs[(32 + r32) * 72 + kc * 16 + h32 * 8]);
      a0 = __builtin_amdgcn_mfma_f32_32x32x16_bf16(vf0, pfrag, a0, 0, 0, 0);
      a1 = __builtin_amdgcn_mfma_f32_32x32x16_bf16(vf1, pfrag, a1, 0, 0, 0);
    }
  }
}

__global__ __launch_bounds__(256, 4) void attn_kernel(const u16* __restrict__ Q,
                                                      const u16* __restrict__ K,
                                                      const u16* __restrict__ Vt,
                                                      u16* __restrict__ out) {
  const int tid  = threadIdx.x;
  const int lane = tid & 63;
  const int wave = tid >> 6;
  const int r32  = lane & 31;
  const int h32  = lane >> 5;
  const int bh   = blockIdx.y;
  const int q0   = blockIdx.x * 128 + wave * 32;

  __shared__ __align__(16) u16 Ks[2][64 * 72];   // stride 72 -> conflict-free
  __shared__ __align__(16) u16 Vs[2][64 * 72];

  const u16* kbase = K  + (size_t)bh * S_ * HD_;
  const u16* vbase = Vt + (size_t)bh * HD_ * S_;
  const int ra = tid >> 3;             // rows 0..31
  const int rb = ra + 32;              // rows 32..63
  const int ca = (tid & 7) * 8;

  bf16x8 qf[4];
  {
    const u16* qbase = Q + (size_t)(bh * S_ + q0 + r32) * HD_ + h32 * 8;
#pragma unroll
    for (int dc = 0; dc < 4; ++dc)
      qf[dc] = *reinterpret_cast<const bf16x8*>(qbase + dc * 16);
  }

  f32x16 a0 = zero16(), a1 = zero16();
  float lsum = 0.f;

  // prologue: tile 0 -> set0 -> buf0; tile 1 -> set1
  uint4 k0a = *reinterpret_cast<const uint4*>(&kbase[(size_t)ra * HD_ + ca]);
  uint4 k0b = *reinterpret_cast<const uint4*>(&kbase[(size_t)rb * HD_ + ca]);
  uint4 v0a = *reinterpret_cast<const uint4*>(&vbase[(size_t)ra * S_ + ca]);
  uint4 v0b = *reinterpret_cast<const uint4*>(&vbase[(size_t)rb * S_ + ca]);
  *reinterpret_cast<uint4*>(&Ks[0][ra * 72 + ca]) = k0a;
  *reinterpret_cast<uint4*>(&Ks[0][rb * 72 + ca]) = k0b;
  *reinterpret_cast<uint4*>(&Vs[0][ra * 72 + ca]) = v0a;
  *reinterpret_cast<uint4*>(&Vs[0][rb * 72 + ca]) = v0b;
  uint4 k1a = *reinterpret_cast<const uint4*>(&kbase[(size_t)(64 + ra) * HD_ + ca]);
  uint4 k1b = *reinterpret_cast<const uint4*>(&kbase[(size_t)(64 + rb) * HD_ + ca]);
  uint4 v1a = *reinterpret_cast<const uint4*>(&vbase[(size_t)ra * S_ + 64 + ca]);
  uint4 v1b = *reinterpret_cast<const uint4*>(&vbase[(size_t)rb * S_ + 64 + ca]);
  __syncthreads();

  const int NT = S_ / 64;   // 32, even
  for (int kt = 0; kt < NT; kt += 2) {
    // ---- even: compute buf0, write set1 -> buf1, load kt+2 -> set0 ----
    attn_compute(Ks[0], Vs[0], qf, r32, h32, a0, a1, lsum);
    *reinterpret_cast<uint4*>(&Ks[1][ra * 72 + ca]) = k1a;
    *reinterpret_cast<uint4*>(&Ks[1][rb * 72 + ca]) = k1b;
    *reinterpret_cast<uint4*>(&Vs[1][ra * 72 + ca]) = v1a;
    *reinterpret_cast<uint4*>(&Vs[1][rb * 72 + ca]) = v1b;
    {
      int kn = (kt + 2 < NT ? kt + 2 : NT - 1) * 64;
      k0a = *reinterpret_cast<const uint4*>(&kbase[(size_t)(kn + ra) * HD_ + ca]);
      k0b = *reinterpret_cast<const uint4*>(&kbase[(size_t)(kn + rb) * HD_ + ca]);
      v0a = *reinterpret_cast<const uint4*>(&vbase[(size_t)ra * S_ + kn + ca]);
      v0b = *reinterpret_cast<const uint4*>(&vbase[(size_t)rb * S_ + kn + ca]);
    }
    __syncthreads();

    // ---- odd: compute buf1, write set0 -> buf0, load kt+3 -> set1 ----
    attn_compute(Ks[1], Vs[1], qf, r32, h32, a0, a1, lsum);
    *reinterpret_cast<uint4*>(&Ks[0][ra * 72 + ca]) = k0a;
    *reinterpret_cast<uint4*>(&Ks[0][rb * 72 + ca]) = k0b;
    *reinterpret_cast<uint4*>(&Vs[0][ra * 72 + ca]) = v0a;
    *reinterpret_cast<uint4*>(&Vs[0][rb * 72 + ca]) = v0b;
    {
      int kn = (kt + 3 < NT ? kt + 3 : NT - 1) * 64;
      k1a = *reinterpret_cast<const uint4*>(&kbase[(size_t)(kn + ra) * HD_ + ca]);
      k1b = *reinterpret_cast<const uint4*>(&kbase[(size_t)(kn + rb) * HD_ + ca]);
      v1a = *reinterpret_cast<const uint4*>(&vbase[(size_t)ra * S_ + kn + ca]);
      v1b = *reinterpret_cast<const uint4*>(&vbase[(size_t)rb * S_ + kn + ca]);
    }
    __syncthreads();
  }

  // epilogue: O^T regs -> out[b, s, h*64+d]; d = 8g + 4*h32 (+32 for a1)
  const int b = bh >> 4, hh = bh & 15;
  float lt  = lsum + __shfl_xor(lsum, 32);
  float inv = 1.f / lt;
  int srow = q0 + r32;
  u16* orow = out + (size_t)(b * S_ + srow) * D_ + hh * HD_;
#pragma unroll
  for (int g = 0; g < 4; ++g) {
    uint2 w;
    w.x = pack_bf(a0[4 * g + 0] * inv, a0[4 * g + 1] * inv);
    w.y = pack_bf(a0[4 * g + 2] * inv, a0[4 * g + 3] * inv);
    *reinterpret_cast<uint2*>(orow + 8 * g + 4 * h32) = w;
    w.x = pack_bf(a1[4 * g + 0] * inv, a1[4 * g + 1] * inv);
    w.y = pack_bf(a1[4 * g + 2] * inv, a1[4 * g + 3] * inv);
    *reinterpret_cast<uint2*>(orow + 32 + 8 * g + 4 * h32) = w;
  }
}

// ---------------- layernorm ----------------
__global__ __launch_bounds__(256) void ln_kernel(const float* __restrict__ X,
                                                 const float* __restrict__ w,
                                                 const float* __restrict__ b,
                                                 float* __restrict__ out) {
  const int row = blockIdx.x;
  const int tid = threadIdx.x;
  const float* x = X + (size_t)row * 1024;
  float vals[4];
  float s = 0.f, s2 = 0.f;
#pragma unroll
  for (int i = 0; i < 4; ++i) {
    float v = x[tid + i * 256];
    vals[i] = v;
    s += v;
    s2 += v * v;
  }
#pragma unroll
  for (int off = 32; off; off >>= 1) {
    s  += __shfl_xor(s, off);
    s2 += __shfl_xor(s2, off);
  }
  __shared__ float a1[4], a2[4];
  if ((tid & 63) == 0) { a1[tid >> 6] = s; a2[tid >> 6] = s2; }
  __syncthreads();
  s  = a1[0] + a1[1] + a1[2] + a1[3];
  s2 = a2[0] + a2[1] + a2[2] + a2[3];
  float mu  = s * (1.f / 1024.f);
  float var = s2 * (1.f / 1024.f) - mu * mu;
  float inv = rsqrtf(var + 1e-5f);
#pragma unroll
  for (int i = 0; i < 4; ++i) {
    int c = tid + i * 256;
    out[(size_t)row * 1024 + c] = (vals[i] - mu) * inv * w[c] + b[c];
  }
}

// ---------------- launch ----------------
extern "C" void kernel_launch(void* const* d_in, const int* in_sizes, int n_in,
                              void* d_out, int out_size, void* d_ws, size_t ws_size,
                              hipStream_t stream) {
  const float* x   = (const float*)d_in[0];
  const float* Wq  = (const float*)d_in[1];
  const float* bq  = (const float*)d_in[2];
  const float* Wk  = (const float*)d_in[3];
  const float* bk  = (const float*)d_in[4];
  const float* Wv  = (const float*)d_in[5];
  const float* bv  = (const float*)d_in[6];
  const float* Wo  = (const float*)d_in[7];
  const float* bo  = (const float*)d_in[8];
  const float* lnw = (const float*)d_in[9];
  const float* lnb = (const float*)d_in[10];

  const size_t MB = 1024ull * 1024ull;
  char* ws = (char*)d_ws;
  u16* xb  = (u16*)(ws + 0);        // 16 MB; later reused as attention output
  u16* Qb  = (u16*)(ws + 16 * MB);  // 16 MB
  u16* Kb  = (u16*)(ws + 32 * MB);  // 16 MB
  u16* Vtb = (u16*)(ws + 48 * MB);  // 16 MB
  u16* Wqb = (u16*)(ws + 64 * MB);  // 2 MB each
  u16* Wkb = (u16*)(ws + 66 * MB);
  u16* Wvb = (u16*)(ws + 68 * MB);
  u16* Wob = (u16*)(ws + 70 * MB);
  float* Of = (float*)(ws + 16 * MB); // 32 MB, overlaps Qb/Kb (dead after attention)

  cast_all<<<8192 + 4096, 256, 0, stream>>>(x, Wq, Wk, Wv, Wo, xb, Wqb, Wkb, Wvb, Wob);

  gemm_qkv<<<dim3((M_ / 128) * 3, D_ / 128), 256, 0, stream>>>(
      xb, Wqb, Wkb, Wvb, bq, bk, bv, Qb, Kb, Vtb);

  attn_kernel<<<dim3(S_ / 128, B_ * H_), 256, 0, stream>>>(Qb, Kb, Vtb, xb);

  gemm_bt<<<dim3(M_ / 128, D_ / 128), 256, 0, stream>>>(xb, Wob, bo, Of);

  ln_kernel<<<M_, 256, 0, stream>>>(Of, lnw, lnb, (float*)d_out);
}